// Round 6
// baseline (366.927 us; speedup 1.0000x reference)
//
#include <hip/hip_runtime.h>
#include <cstdint>
#include <cstddef>

#define B_   32
#define TIN  512
#define D_   384
#define F_   384
#define TOUT 4096

typedef __bf16 bf16x8 __attribute__((ext_vector_type(8)));
typedef float  f32x4  __attribute__((ext_vector_type(4)));
typedef unsigned short u16x8 __attribute__((ext_vector_type(8)));

__device__ __forceinline__ unsigned short f2bf(float f) {
  unsigned int u = __float_as_uint(f);
  u += 0x7fff + ((u >> 16) & 1);   // round-to-nearest-even
  return (unsigned short)(u >> 16);
}

// ---------------------------------------------------------------- prep (weights)
// 1152 blocks x 256: thread e reads w[e*3..+2] (f32, [F][D][K]), writes
// Wt[k][f][d] bf16.
__global__ __launch_bounds__(256) void prep_w(
    const float* __restrict__ w1, const float* __restrict__ w2,
    unsigned short* __restrict__ Wt1, unsigned short* __restrict__ Wt2) {
  int g = blockIdx.x * 256 + threadIdx.x;     // < 294912
  const int FD = F_ * D_;                     // 147456
  int which = g >= FD;
  const float* w = which ? w2 : w1;
  unsigned short* o = which ? Wt2 : Wt1;
  int e = g - which * FD;                     // f*D_+d
  o[e]          = f2bf(w[e * 3 + 0]);
  o[FD + e]     = f2bf(w[e * 3 + 1]);
  o[2 * FD + e] = f2bf(w[e * 3 + 2]);
}

// ---------------------------------------------------------------- fused kernel
// Grid 1536 x 512thr, LDS 31,104B -> 4 blocks/CU (thread-limited, 32 waves).
// bx < 512  : conv block, 32 output rows (conv1+LN+relu in LDS -> conv2+LN+dot
//             -> dur). Barrier-free MFMA loops; A/h1 in 27.6KB swizzled LDS;
//             B global->reg with 1-step prefetch (Wt L2-resident).
// bx >= 512 : gather block: 128 contiguous out-rows of one batch; wave-shfl
//             cumsum (2 barriers), binary search, 196KB NT loads+stores.
#define NCONV 512
#define NGATH 1024

__global__ __launch_bounds__(512, 4) void fused(
    const unsigned short* __restrict__ Wt1, const unsigned short* __restrict__ Wt2,
    const float* __restrict__ b1, const float* __restrict__ g1, const float* __restrict__ be1,
    const float* __restrict__ b2, const float* __restrict__ g2, const float* __restrict__ be2,
    const float* __restrict__ lw, const float* __restrict__ lb,
    float* __restrict__ dur, const int* __restrict__ target,
    const f32x4* __restrict__ x4, f32x4* __restrict__ out4) {
  __shared__ __attribute__((aligned(16))) char smem[31104];
  // conv:   As 36 rows x 768B = [0,27648)  (x bf16 swizzled; h1 aliases rows 0..33)
  //         stats [48][8][2] f32 = [27648,30720) ; stats2 [48][2] f32 = [30720,31104)
  // gather: ends[512] int = [0,2048) ; wsum[8] = [2048,2080) ; idx_s[128] = [2080,2592)

  const int tid = threadIdx.x;
  const int bx  = blockIdx.x;

  if (bx >= NCONV) {
    // ---------------- gather
    int gi = bx - NCONV;                      // 0..1023
    int* ends  = (int*)smem;
    int* wsum  = (int*)(smem + 2048);
    int* idx_s = (int*)(smem + 2080);
    int b  = gi >> 5;
    int r0 = (gi & 31) * 128;
    int lane = tid & 63, wave = tid >> 6;
    int v = target[b * TIN + tid];
    for (int off = 1; off < 64; off <<= 1) {  // wave-inclusive scan
      int t = __shfl_up(v, off);
      if (lane >= off) v += t;
    }
    if (lane == 63) wsum[wave] = v;
    __syncthreads();
    int base = 0;
    for (int w = 0; w < 8; ++w) base += (w < wave) ? wsum[w] : 0;
    ends[tid] = v + base;                     // inclusive cumsum over 512
    __syncthreads();
    if (tid < 128) {
      int m = r0 + tid;
      int lo = 0, hi = 512;                   // first j with ends[j] > m
      while (lo < hi) {
        int mid = (lo + hi) >> 1;
        if (ends[mid] <= m) lo = mid + 1; else hi = mid;
      }
      idx_s[tid] = (lo < TIN) ? lo : -1;
    }
    __syncthreads();
    const f32x4* xb = x4 + (size_t)b * (TIN * 96);
    f32x4* ob = out4 + ((size_t)b * TOUT + r0) * 96;
    #pragma unroll 4
    for (int it = 0; it < 24; ++it) {
      int j = it * 512 + tid;                 // 0..12287
      int row = j / 96;
      int c = j - row * 96;
      int id = idx_s[row];
      f32x4 v4 = {0.f, 0.f, 0.f, 0.f};
      if (id >= 0) v4 = __builtin_nontemporal_load(xb + id * 96 + c);  // keep L2 for Wt
      __builtin_nontemporal_store(v4, ob + j);                          // never re-read
    }
    return;
  }

  // ---------------- conv block: 32 output rows
  char* As = smem;
  float* stats  = (float*)(smem + 27648);     // [48][8][2]
  float* stats2 = (float*)(smem + 30720);     // [48][2] (mean, rstd)

  const int wave = tid >> 6;        // 0..7
  const int lane = tid & 63;
  const int quad = lane >> 4;
  const int l15  = lane & 15;
  const int wn   = wave * 48;
  const int m0   = bx * 32;
  const int b    = m0 >> 9;         // 32-row tiles never cross batch
  const int t0   = m0 & 511;

  // ---- stage A once: rows 0..35 = x[t0-2 .. t0+33], bf16, swizzled
  for (int p = 0; p < 4; ++p) {
    int ch = p * 512 + tid;
    if (ch < 1728) {                          // 36*48
      int row = ch / 48;
      int ci  = ch - row * 48;
      int t   = t0 - 2 + row;
      u16x8 val;
      if ((unsigned)t >= (unsigned)TIN) {
        val = (u16x8)0;
      } else {
        const f32x4* xr = x4 + ((size_t)(b * TIN + t)) * 96 + ci * 2;
        f32x4 v0 = xr[0], v1 = xr[1];
        val[0] = f2bf(v0[0]); val[1] = f2bf(v0[1]); val[2] = f2bf(v0[2]); val[3] = f2bf(v0[3]);
        val[4] = f2bf(v1[0]); val[5] = f2bf(v1[1]); val[6] = f2bf(v1[2]); val[7] = f2bf(v1[3]);
      }
      unsigned int byte = ((unsigned int)(row * 768 + ci * 16)) ^ (((unsigned)row & 7u) << 4);
      *(u16x8*)(As + byte) = val;
    }
  }
  __syncthreads();

  // ================ conv1: 48-row tile (rows 0..33 used), acc 3x3, no barriers
  f32x4 acc[3][3];
  for (int i = 0; i < 3; ++i)
    for (int j = 0; j < 3; ++j)
      acc[i][j] = (f32x4){0.f, 0.f, 0.f, 0.f};

  {
    const unsigned short* Bb = Wt1 + (size_t)(wn + l15) * D_ + quad * 8;
    bf16x8 bvn[3];
    for (int ni = 0; ni < 3; ++ni)
      bvn[ni] = *(const bf16x8*)(Bb + ni * (16 * D_));
    #pragma unroll 1
    for (int kc = 0; kc < 36; ++kc) {
      bf16x8 bv[3];
      bv[0] = bvn[0]; bv[1] = bvn[1]; bv[2] = bvn[2];
      if (kc < 35) {                          // prefetch next k-step's B frags
        int kn = kc + 1;
        int kw2 = kn / 12, d02 = (kn - kw2 * 12) * 32;
        const unsigned short* Bk = Bb + (size_t)kw2 * (F_ * D_) + d02;
        for (int ni = 0; ni < 3; ++ni)
          bvn[ni] = *(const bf16x8*)(Bk + ni * (16 * D_));
      }
      int kw = kc / 12, d0 = (kc - kw * 12) * 32;
      unsigned int rb = (unsigned)(l15 + kw);
      unsigned int sw = (rb & 7u) << 4;
      unsigned int co = (unsigned)(d0 * 2 + quad * 16);
      bf16x8 av[3];
      av[0] = *(const bf16x8*)(As + ((rb * 768 + co) ^ sw));
      av[1] = *(const bf16x8*)(As + (((rb + 16) * 768 + co) ^ sw));
      unsigned int r2 = rb + 32; if (r2 > 35u) r2 = 35u;   // clamp garbage rows
      av[2] = *(const bf16x8*)(As + ((r2 * 768 + co) ^ sw));
      for (int mi = 0; mi < 3; ++mi)
        for (int ni = 0; ni < 3; ++ni)
          acc[mi][ni] = __builtin_amdgcn_mfma_f32_16x16x32_bf16(av[mi], bv[ni], acc[mi][ni], 0, 0, 0);
    }
  }

  // ================ epilogue 1: LN(+bias)+relu -> h1 bf16 into As rows 0..33
  {
    float g1v[3], be1v[3], bb1[3];
    for (int ni = 0; ni < 3; ++ni) {
      int c = wn + ni * 16 + l15;
      g1v[ni] = g1[c]; be1v[ni] = be1[c]; bb1[ni] = b1[c];
    }
    for (int mi = 0; mi < 3; ++mi)
      for (int r = 0; r < 4; ++r) {
        float s = 0.f, ssq = 0.f;
        for (int ni = 0; ni < 3; ++ni) {
          float y = acc[mi][ni][r] + bb1[ni];
          s += y; ssq += y * y;
        }
        for (int off = 1; off < 16; off <<= 1) {   // reduce over quad's 16 lanes
          s   += __shfl_xor(s, off);
          ssq += __shfl_xor(ssq, off);
        }
        if (l15 == 0) {
          int row = mi * 16 + quad * 4 + r;
          stats[(row * 8 + wave) * 2 + 0] = s;
          stats[(row * 8 + wave) * 2 + 1] = ssq;
        }
      }
    __syncthreads();
    if (tid < 48) {
      float s = 0.f, ssq = 0.f;
      for (int w = 0; w < 8; ++w) {
        s   += stats[(tid * 8 + w) * 2 + 0];
        ssq += stats[(tid * 8 + w) * 2 + 1];
      }
      float mean = s * (1.f / 384.f);
      float var  = ssq * (1.f / 384.f) - mean * mean;
      stats2[tid * 2 + 0] = mean;
      stats2[tid * 2 + 1] = rsqrtf(var + 1e-5f);
    }
    __syncthreads();
    for (int mi = 0; mi < 3; ++mi)
      for (int r = 0; r < 4; ++r) {
        int row = mi * 16 + quad * 4 + r;
        if (row < 34) {
          float mean = stats2[row * 2 + 0];
          float rstd = stats2[row * 2 + 1];
          int th = t0 - 1 + row;                         // global h1 time
          bool valid = (unsigned)th < (unsigned)TIN;     // t=-1/512 -> zero pad
          unsigned int hb = (((unsigned)row) & 7u) << 4;
          for (int ni = 0; ni < 3; ++ni) {
            float y = (acc[mi][ni][r] + bb1[ni] - mean) * rstd * g1v[ni] + be1v[ni];
            y = y > 0.f ? y : 0.f;
            if (!valid) y = 0.f;
            unsigned int byte = ((unsigned int)(row * 768 + (wn + ni * 16 + l15) * 2)) ^ hb;
            *(unsigned short*)(As + byte) = f2bf(y);
          }
        }
      }
    __syncthreads();                                     // h1 visible
  }

  // ================ conv2: 32-row tile from h1 (LDS), acc 2x3, no barriers
  f32x4 acc2[2][3];
  for (int i = 0; i < 2; ++i)
    for (int j = 0; j < 3; ++j)
      acc2[i][j] = (f32x4){0.f, 0.f, 0.f, 0.f};

  {
    const unsigned short* Bb = Wt2 + (size_t)(wn + l15) * D_ + quad * 8;
    bf16x8 bvn[3];
    for (int ni = 0; ni < 3; ++ni)
      bvn[ni] = *(const bf16x8*)(Bb + ni * (16 * D_));
    #pragma unroll 1
    for (int kc = 0; kc < 36; ++kc) {
      bf16x8 bv[3];
      bv[0] = bvn[0]; bv[1] = bvn[1]; bv[2] = bvn[2];
      if (kc < 35) {
        int kn = kc + 1;
        int kw2 = kn / 12, d02 = (kn - kw2 * 12) * 32;
        const unsigned short* Bk = Bb + (size_t)kw2 * (F_ * D_) + d02;
        for (int ni = 0; ni < 3; ++ni)
          bvn[ni] = *(const bf16x8*)(Bk + ni * (16 * D_));
      }
      int kw = kc / 12, d0 = (kc - kw * 12) * 32;
      unsigned int rb = (unsigned)(l15 + kw);            // h1 row = m + kw (<=33)
      unsigned int sw = (rb & 7u) << 4;
      unsigned int co = (unsigned)(d0 * 2 + quad * 16);
      bf16x8 av[2];
      av[0] = *(const bf16x8*)(As + ((rb * 768 + co) ^ sw));
      av[1] = *(const bf16x8*)(As + (((rb + 16) * 768 + co) ^ sw));
      for (int mi = 0; mi < 2; ++mi)
        for (int ni = 0; ni < 3; ++ni)
          acc2[mi][ni] = __builtin_amdgcn_mfma_f32_16x16x32_bf16(av[mi], bv[ni], acc2[mi][ni], 0, 0, 0);
    }
  }

  // ================ epilogue 2: LN(+bias)+relu+dot(lin_w)+lb -> dur
  {
    float g2v[3], be2v[3], lwv[3], bb2[3];
    for (int ni = 0; ni < 3; ++ni) {
      int c = wn + ni * 16 + l15;
      g2v[ni] = g2[c]; be2v[ni] = be2[c]; lwv[ni] = lw[c]; bb2[ni] = b2[c];
    }
    for (int mi = 0; mi < 2; ++mi)
      for (int r = 0; r < 4; ++r) {
        float s = 0.f, ssq = 0.f;
        for (int ni = 0; ni < 3; ++ni) {
          float y = acc2[mi][ni][r] + bb2[ni];
          s += y; ssq += y * y;
        }
        for (int off = 1; off < 16; off <<= 1) {
          s   += __shfl_xor(s, off);
          ssq += __shfl_xor(ssq, off);
        }
        if (l15 == 0) {
          int row = mi * 16 + quad * 4 + r;
          stats[(row * 8 + wave) * 2 + 0] = s;
          stats[(row * 8 + wave) * 2 + 1] = ssq;
        }
      }
    __syncthreads();
    if (tid < 32) {
      float s = 0.f, ssq = 0.f;
      for (int w = 0; w < 8; ++w) {
        s   += stats[(tid * 8 + w) * 2 + 0];
        ssq += stats[(tid * 8 + w) * 2 + 1];
      }
      float mean = s * (1.f / 384.f);
      float var  = ssq * (1.f / 384.f) - mean * mean;
      stats2[tid * 2 + 0] = mean;
      stats2[tid * 2 + 1] = rsqrtf(var + 1e-5f);
    }
    __syncthreads();
    for (int mi = 0; mi < 2; ++mi)
      for (int r = 0; r < 4; ++r) {
        int row = mi * 16 + quad * 4 + r;
        float mean = stats2[row * 2 + 0];
        float rstd = stats2[row * 2 + 1];
        float a = 0.f;
        for (int ni = 0; ni < 3; ++ni) {
          float y = (acc2[mi][ni][r] + bb2[ni] - mean) * rstd * g2v[ni] + be2v[ni];
          y = y > 0.f ? y : 0.f;
          a += y * lwv[ni];
        }
        for (int off = 1; off < 16; off <<= 1) a += __shfl_xor(a, off);
        if (l15 == 0) stats[(row * 8 + wave) * 2 + 0] = a;
      }
    __syncthreads();
    if (tid < 32) {
      float a = 0.f;
      for (int w = 0; w < 8; ++w) a += stats[(tid * 8 + w) * 2 + 0];
      dur[m0 + tid] = a + lb[0];
    }
  }
}

// ---------------------------------------------------------------- launch
extern "C" void kernel_launch(void* const* d_in, const int* in_sizes, int n_in,
                              void* d_out, int out_size, void* d_ws, size_t ws_size,
                              hipStream_t stream) {
  const float* x      = (const float*)d_in[0];
  const int*   target = (const int*)d_in[1];
  const float* w1  = (const float*)d_in[3];
  const float* b1  = (const float*)d_in[4];
  const float* g1  = (const float*)d_in[5];
  const float* be1 = (const float*)d_in[6];
  const float* w2  = (const float*)d_in[7];
  const float* b2  = (const float*)d_in[8];
  const float* g2  = (const float*)d_in[9];
  const float* be2 = (const float*)d_in[10];
  const float* lw  = (const float*)d_in[11];
  const float* lb  = (const float*)d_in[12];

  float* out = (float*)d_out;
  float* dur = out + (size_t)B_ * TOUT * D_;   // outputs concatenated flat

  char* ws = (char*)d_ws;
  unsigned short* Wt1 = (unsigned short*)(ws);            // 884,736 B
  unsigned short* Wt2 = (unsigned short*)(ws + 884736);   // 884,736 B

  prep_w<<<dim3(1152), dim3(256), 0, stream>>>(w1, w2, Wt1, Wt2);
  fused<<<dim3(NCONV + NGATH), dim3(512), 0, stream>>>(
      Wt1, Wt2, b1, g1, be1, b2, g2, be2, lw, lb,
      dur, target, (const f32x4*)x, (f32x4*)out);
}

// Round 7
// 332.491 us; speedup vs baseline: 1.1036x; 1.1036x over previous
//
#include <hip/hip_runtime.h>
#include <cstdint>
#include <cstddef>

#define B_   32
#define TIN  512
#define D_   384
#define F_   384
#define TOUT 4096

typedef __bf16 bf16x8 __attribute__((ext_vector_type(8)));
typedef float  f32x4  __attribute__((ext_vector_type(4)));
typedef unsigned short u16x8 __attribute__((ext_vector_type(8)));

__device__ __forceinline__ unsigned short f2bf(float f) {
  unsigned int u = __float_as_uint(f);
  u += 0x7fff + ((u >> 16) & 1);   // round-to-nearest-even
  return (unsigned short)(u >> 16);
}

// ---------------------------------------------------------------- gather+prep
// Grid 3200 x 256thr, ~3.3KB LDS, ~30 VGPR -> 8 blocks/CU (32 waves/CU).
// Gather is occupancy-hungry (dependent idx->load->store chains); conv is
// VGPR-hungry (110 live regs). Round 6 proved they can't share one launch
// config: 31KB LDS let the compiler target 8 waves/EU -> VGPR 48 -> spilled
// MFMA loop (MfmaUtil 8%). So gather runs alone at full wave count.
// bx <  2048 : gather slab = 64 contiguous out-rows of one batch; in-block
//              cumsum, binary search, 98KB NT stores.
// bx >= 2048 : weight transpose (1152 blocks): Wt[k][f][d] bf16; ready
//              before the conv dispatch by stream order.
#define GB 2048

__global__ __launch_bounds__(256) void gather_prep(
    const float* __restrict__ w1, const float* __restrict__ w2,
    unsigned short* __restrict__ Wt1, unsigned short* __restrict__ Wt2,
    const int* __restrict__ target,
    const f32x4* __restrict__ x4, f32x4* __restrict__ out4) {
  int bx = blockIdx.x;
  int tid = threadIdx.x;

  if (bx < GB) {
    __shared__ int ends[512];
    __shared__ int ps[256];
    __shared__ int idx_s[64];
    int b  = bx >> 6;                         // 64 slabs per batch
    int r0 = (bx & 63) * 64;
    int a0 = target[b * TIN + 2 * tid];
    int a1 = target[b * TIN + 2 * tid + 1];
    ps[tid] = a0 + a1;
    __syncthreads();
    for (int off = 1; off < 256; off <<= 1) {
      int add = (tid >= off) ? ps[tid - off] : 0;
      __syncthreads();
      ps[tid] += add;
      __syncthreads();
    }
    int incl = ps[tid];
    ends[2 * tid + 1] = incl;
    ends[2 * tid]     = incl - a1;
    __syncthreads();
    if (tid < 64) {
      int m = r0 + tid;
      int lo = 0, hi = 512;                   // first j with ends[j] > m
      while (lo < hi) {
        int mid = (lo + hi) >> 1;
        if (ends[mid] <= m) lo = mid + 1; else hi = mid;
      }
      idx_s[tid] = (lo < TIN) ? lo : -1;
    }
    __syncthreads();
    const f32x4* xb = x4 + (size_t)b * (TIN * 96);
    f32x4* ob = out4 + ((size_t)b * TOUT + r0) * 96;
    #pragma unroll 8
    for (int it = 0; it < 24; ++it) {
      int j = it * 256 + tid;                 // 0..6143
      int row = j / 96;
      int c = j - row * 96;
      int id = idx_s[row];
      f32x4 v = {0.f, 0.f, 0.f, 0.f};
      if (id >= 0) v = xb[id * 96 + c];
      __builtin_nontemporal_store(v, ob + j); // out never re-read
    }
    return;
  }
  bx -= GB;

  {
    int g = bx * 256 + tid;                   // < 294912
    const int FD = F_ * D_;                   // 147456
    int which = g >= FD;
    const float* w = which ? w2 : w1;
    unsigned short* o = which ? Wt2 : Wt1;
    int e = g - which * FD;                   // f*D_+d
    o[e]          = f2bf(w[e * 3 + 0]);
    o[FD + e]     = f2bf(w[e * 3 + 1]);
    o[2 * FD + e] = f2bf(w[e * 3 + 2]);
  }
}

// ---------------------------------------------------------------- conv kernel
// 256 blocks x 512thr x 68.7KB LDS. LDS caps occupancy at 4 waves/EU, which
// keeps the compiler's VGPR budget at 128 -> no spill (round-5-verified:
// this exact structure ran inside a passing 283.5µs bench). Barrier-free
// MFMA loops; A/h1 swizzled in LDS; B global->reg 1-step prefetch; LN via
// quad-shfl partials.
__global__ __launch_bounds__(512, 4) void conv(
    const unsigned short* __restrict__ Wt1, const unsigned short* __restrict__ Wt2,
    const float* __restrict__ b1, const float* __restrict__ g1, const float* __restrict__ be1,
    const float* __restrict__ b2, const float* __restrict__ g2, const float* __restrict__ be2,
    const float* __restrict__ lw, const float* __restrict__ lb,
    float* __restrict__ dur, const f32x4* __restrict__ x4) {
  __shared__ __attribute__((aligned(16))) char smem[68736];
  char* As = smem;                            // 82 rows x 768B = [0,62976)
  float* stats  = (float*)(smem + 62976);     // [80][8][2]
  float* stats2 = (float*)(smem + 68096);     // [80][2] (mean, rstd)

  const int tid = threadIdx.x;
  const int wave = tid >> 6;        // 0..7
  const int lane = tid & 63;
  const int quad = lane >> 4;
  const int l15  = lane & 15;
  const int wn   = wave * 48;
  const int m0   = blockIdx.x * 64;
  const int b    = m0 >> 9;         // 64-row tiles never cross batch
  const int t0   = m0 & 511;

  // ---- stage A once: rows 0..67 = x[t0-2 .. t0+65], bf16, swizzled
  for (int p = 0; p < 7; ++p) {
    int ch = p * 512 + tid;
    if (ch < 3264) {                          // 68*48
      int row = ch / 48;
      int ci  = ch - row * 48;
      int t   = t0 - 2 + row;
      u16x8 val;
      if ((unsigned)t >= (unsigned)TIN) {
        val = (u16x8)0;
      } else {
        const f32x4* xr = x4 + ((size_t)(b * TIN + t)) * 96 + ci * 2;
        f32x4 v0 = xr[0], v1 = xr[1];
        val[0] = f2bf(v0[0]); val[1] = f2bf(v0[1]); val[2] = f2bf(v0[2]); val[3] = f2bf(v0[3]);
        val[4] = f2bf(v1[0]); val[5] = f2bf(v1[1]); val[6] = f2bf(v1[2]); val[7] = f2bf(v1[3]);
      }
      unsigned int byte = ((unsigned int)(row * 768 + ci * 16)) ^ (((unsigned)row & 7u) << 4);
      *(u16x8*)(As + byte) = val;
    }
  }
  __syncthreads();

  // ================ conv1: 80-row tile (rows 0..65 used), acc 5x3, no barriers
  f32x4 acc[5][3];
  for (int i = 0; i < 5; ++i)
    for (int j = 0; j < 3; ++j)
      acc[i][j] = (f32x4){0.f, 0.f, 0.f, 0.f};

  {
    const unsigned short* Bb = Wt1 + (size_t)(wn + l15) * D_ + quad * 8;
    bf16x8 bvn[3];
    for (int ni = 0; ni < 3; ++ni)
      bvn[ni] = *(const bf16x8*)(Bb + ni * (16 * D_));
    #pragma unroll 1
    for (int kc = 0; kc < 36; ++kc) {
      bf16x8 bv[3];
      bv[0] = bvn[0]; bv[1] = bvn[1]; bv[2] = bvn[2];
      if (kc < 35) {                          // prefetch next k-step's B frags
        int kn = kc + 1;
        int kw2 = kn / 12, d02 = (kn - kw2 * 12) * 32;
        const unsigned short* Bk = Bb + (size_t)kw2 * (F_ * D_) + d02;
        for (int ni = 0; ni < 3; ++ni)
          bvn[ni] = *(const bf16x8*)(Bk + ni * (16 * D_));
      }
      int kw = kc / 12, d0 = (kc - kw * 12) * 32;
      int rb = l15 + kw;
      unsigned int sw = (((unsigned)rb) & 7u) << 4;
      unsigned int base = (unsigned int)(rb * 768 + d0 * 2 + quad * 16);
      bf16x8 av[5];
      for (int mi = 0; mi < 5; ++mi)
        av[mi] = *(const bf16x8*)(As + ((base + mi * 12288) ^ sw));
      for (int mi = 0; mi < 5; ++mi)
        for (int ni = 0; ni < 3; ++ni)
          acc[mi][ni] = __builtin_amdgcn_mfma_f32_16x16x32_bf16(av[mi], bv[ni], acc[mi][ni], 0, 0, 0);
    }
  }

  // ================ epilogue 1: LN(+bias)+relu -> h1 bf16 into As rows 0..65
  {
    float g1v[3], be1v[3], bb1[3];
    for (int ni = 0; ni < 3; ++ni) {
      int c = wn + ni * 16 + l15;
      g1v[ni] = g1[c]; be1v[ni] = be1[c]; bb1[ni] = b1[c];
    }
    for (int mi = 0; mi < 5; ++mi)
      for (int r = 0; r < 4; ++r) {
        float s = 0.f, ssq = 0.f;
        for (int ni = 0; ni < 3; ++ni) {
          float y = acc[mi][ni][r] + bb1[ni];
          s += y; ssq += y * y;
        }
        for (int off = 1; off < 16; off <<= 1) {   // reduce over quad's 16 lanes
          s   += __shfl_xor(s, off);
          ssq += __shfl_xor(ssq, off);
        }
        if (l15 == 0) {
          int row = mi * 16 + quad * 4 + r;
          stats[(row * 8 + wave) * 2 + 0] = s;
          stats[(row * 8 + wave) * 2 + 1] = ssq;
        }
      }
    __syncthreads();
    if (tid < 80) {
      float s = 0.f, ssq = 0.f;
      for (int w = 0; w < 8; ++w) {
        s   += stats[(tid * 8 + w) * 2 + 0];
        ssq += stats[(tid * 8 + w) * 2 + 1];
      }
      float mean = s * (1.f / 384.f);
      float var  = ssq * (1.f / 384.f) - mean * mean;
      stats2[tid * 2 + 0] = mean;
      stats2[tid * 2 + 1] = rsqrtf(var + 1e-5f);
    }
    __syncthreads();
    for (int mi = 0; mi < 5; ++mi)
      for (int r = 0; r < 4; ++r) {
        int row = mi * 16 + quad * 4 + r;
        if (row < 66) {
          float mean = stats2[row * 2 + 0];
          float rstd = stats2[row * 2 + 1];
          int th = t0 - 1 + row;                         // global h1 time
          bool valid = (unsigned)th < (unsigned)TIN;     // t=-1/512 -> zero pad
          unsigned int hb = (((unsigned)row) & 7u) << 4;
          for (int ni = 0; ni < 3; ++ni) {
            float y = (acc[mi][ni][r] + bb1[ni] - mean) * rstd * g1v[ni] + be1v[ni];
            y = y > 0.f ? y : 0.f;
            if (!valid) y = 0.f;
            unsigned int byte = ((unsigned int)(row * 768 + (wn + ni * 16 + l15) * 2)) ^ hb;
            *(unsigned short*)(As + byte) = f2bf(y);
          }
        }
      }
    __syncthreads();                                     // h1 visible
  }

  // ================ conv2: 64-row tile from h1 (LDS), acc 4x3, no barriers
  f32x4 acc2[4][3];
  for (int i = 0; i < 4; ++i)
    for (int j = 0; j < 3; ++j)
      acc2[i][j] = (f32x4){0.f, 0.f, 0.f, 0.f};

  {
    const unsigned short* Bb = Wt2 + (size_t)(wn + l15) * D_ + quad * 8;
    bf16x8 bvn[3];
    for (int ni = 0; ni < 3; ++ni)
      bvn[ni] = *(const bf16x8*)(Bb + ni * (16 * D_));
    #pragma unroll 1
    for (int kc = 0; kc < 36; ++kc) {
      bf16x8 bv[3];
      bv[0] = bvn[0]; bv[1] = bvn[1]; bv[2] = bvn[2];
      if (kc < 35) {
        int kn = kc + 1;
        int kw2 = kn / 12, d02 = (kn - kw2 * 12) * 32;
        const unsigned short* Bk = Bb + (size_t)kw2 * (F_ * D_) + d02;
        for (int ni = 0; ni < 3; ++ni)
          bvn[ni] = *(const bf16x8*)(Bk + ni * (16 * D_));
      }
      int kw = kc / 12, d0 = (kc - kw * 12) * 32;
      int rb = l15 + kw;                       // h1 row = m + kw
      unsigned int sw = (((unsigned)rb) & 7u) << 4;
      unsigned int base = (unsigned int)(rb * 768 + d0 * 2 + quad * 16);
      bf16x8 av[4];
      for (int mi = 0; mi < 4; ++mi)
        av[mi] = *(const bf16x8*)(As + ((base + mi * 12288) ^ sw));
      for (int mi = 0; mi < 4; ++mi)
        for (int ni = 0; ni < 3; ++ni)
          acc2[mi][ni] = __builtin_amdgcn_mfma_f32_16x16x32_bf16(av[mi], bv[ni], acc2[mi][ni], 0, 0, 0);
    }
  }

  // ================ epilogue 2: LN(+bias)+relu+dot(lin_w)+lb -> dur
  {
    float g2v[3], be2v[3], lwv[3], bb2[3];
    for (int ni = 0; ni < 3; ++ni) {
      int c = wn + ni * 16 + l15;
      g2v[ni] = g2[c]; be2v[ni] = be2[c]; lwv[ni] = lw[c]; bb2[ni] = b2[c];
    }
    for (int mi = 0; mi < 4; ++mi)
      for (int r = 0; r < 4; ++r) {
        float s = 0.f, ssq = 0.f;
        for (int ni = 0; ni < 3; ++ni) {
          float y = acc2[mi][ni][r] + bb2[ni];
          s += y; ssq += y * y;
        }
        for (int off = 1; off < 16; off <<= 1) {
          s   += __shfl_xor(s, off);
          ssq += __shfl_xor(ssq, off);
        }
        if (l15 == 0) {
          int row = mi * 16 + quad * 4 + r;
          stats[(row * 8 + wave) * 2 + 0] = s;
          stats[(row * 8 + wave) * 2 + 1] = ssq;
        }
      }
    __syncthreads();
    if (tid < 64) {
      float s = 0.f, ssq = 0.f;
      for (int w = 0; w < 8; ++w) {
        s   += stats[(tid * 8 + w) * 2 + 0];
        ssq += stats[(tid * 8 + w) * 2 + 1];
      }
      float mean = s * (1.f / 384.f);
      float var  = ssq * (1.f / 384.f) - mean * mean;
      stats2[tid * 2 + 0] = mean;
      stats2[tid * 2 + 1] = rsqrtf(var + 1e-5f);
    }
    __syncthreads();
    for (int mi = 0; mi < 4; ++mi)
      for (int r = 0; r < 4; ++r) {
        int row = mi * 16 + quad * 4 + r;
        float mean = stats2[row * 2 + 0];
        float rstd = stats2[row * 2 + 1];
        float a = 0.f;
        for (int ni = 0; ni < 3; ++ni) {
          float y = (acc2[mi][ni][r] + bb2[ni] - mean) * rstd * g2v[ni] + be2v[ni];
          y = y > 0.f ? y : 0.f;
          a += y * lwv[ni];
        }
        for (int off = 1; off < 16; off <<= 1) a += __shfl_xor(a, off);
        if (l15 == 0) stats[(row * 8 + wave) * 2 + 0] = a;
      }
    __syncthreads();
    if (tid < 64) {
      float a = 0.f;
      for (int w = 0; w < 8; ++w) a += stats[(tid * 8 + w) * 2 + 0];
      dur[m0 + tid] = a + lb[0];
    }
  }
}

// ---------------------------------------------------------------- launch
extern "C" void kernel_launch(void* const* d_in, const int* in_sizes, int n_in,
                              void* d_out, int out_size, void* d_ws, size_t ws_size,
                              hipStream_t stream) {
  const float* x      = (const float*)d_in[0];
  const int*   target = (const int*)d_in[1];
  const float* w1  = (const float*)d_in[3];
  const float* b1  = (const float*)d_in[4];
  const float* g1  = (const float*)d_in[5];
  const float* be1 = (const float*)d_in[6];
  const float* w2  = (const float*)d_in[7];
  const float* b2  = (const float*)d_in[8];
  const float* g2  = (const float*)d_in[9];
  const float* be2 = (const float*)d_in[10];
  const float* lw  = (const float*)d_in[11];
  const float* lb  = (const float*)d_in[12];

  float* out = (float*)d_out;
  float* dur = out + (size_t)B_ * TOUT * D_;   // outputs concatenated flat

  char* ws = (char*)d_ws;
  unsigned short* Wt1 = (unsigned short*)(ws);            // 884,736 B
  unsigned short* Wt2 = (unsigned short*)(ws + 884736);   // 884,736 B

  gather_prep<<<dim3(GB + 1152), dim3(256), 0, stream>>>(
      w1, w2, Wt1, Wt2, target, (const f32x4*)x, (f32x4*)out);
  conv<<<dim3(256), dim3(512), 0, stream>>>(
      Wt1, Wt2, b1, g1, be1, b2, g2, be2, lw, lb, dur, (const f32x4*)x);
}

// Round 8
// 285.258 us; speedup vs baseline: 1.2863x; 1.1656x over previous
//
#include <hip/hip_runtime.h>
#include <cstdint>
#include <cstddef>

#define B_   32
#define TIN  512
#define D_   384
#define F_   384
#define TOUT 4096

typedef __bf16 bf16x8 __attribute__((ext_vector_type(8)));
typedef float  f32x4  __attribute__((ext_vector_type(4)));
typedef unsigned short u16x8 __attribute__((ext_vector_type(8)));

__device__ __forceinline__ unsigned short f2bf(float f) {
  unsigned int u = __float_as_uint(f);
  u += 0x7fff + ((u >> 16) & 1);   // round-to-nearest-even
  return (unsigned short)(u >> 16);
}

// ---------------------------------------------------------------- prep (weights)
// 1152 blocks x 256: thread e reads w[e*3..+2] (f32, [F][D][K]), writes
// Wt[k][f][d] bf16. Runs before fused (stream order) so Wt is ready.
__global__ __launch_bounds__(256) void prep_w(
    const float* __restrict__ w1, const float* __restrict__ w2,
    unsigned short* __restrict__ Wt1, unsigned short* __restrict__ Wt2) {
  int g = blockIdx.x * 256 + threadIdx.x;     // < 294912
  const int FD = F_ * D_;                     // 147456
  int which = g >= FD;
  const float* w = which ? w2 : w1;
  unsigned short* o = which ? Wt2 : Wt1;
  int e = g - which * FD;                     // f*D_+d
  o[e]          = f2bf(w[e * 3 + 0]);
  o[FD + e]     = f2bf(w[e * 3 + 1]);
  o[2 * FD + e] = f2bf(w[e * 3 + 2]);
}

// ---------------------------------------------------------------- fused kernel
// R5 structure (283.5µs best): grid 1280 x 512thr, LDS 68,736B -> 2 blocks/CU.
// Ledger (R2/R3/R5/R7): fused@2blk 283.5 < split 331-333 ~ fused@1blk 335.6.
// Fusion wins because gather waves hide conv's B-load stalls and conv MFMA
// hides gather store drain; 16 waves/CU is the ceiling (conv needs 128-VGPR
// class, R6 proved spill below that). This round's change: gather memory ILP
// 4 -> 12 outstanding (R6 FETCH=32MB showed x-reads are cache hits; gather is
// in-flight-bytes limited, 2.2 TB/s at depth 4). 12x f32x4 batch = 48 VGPR,
// statically indexed. Plus 2-barrier wave-shfl scan (R6-proven) vs 18-barrier.
#define NCONV 256
#define NGATH 1024

__global__ __launch_bounds__(512, 4) void fused(
    const unsigned short* __restrict__ Wt1, const unsigned short* __restrict__ Wt2,
    const float* __restrict__ b1, const float* __restrict__ g1, const float* __restrict__ be1,
    const float* __restrict__ b2, const float* __restrict__ g2, const float* __restrict__ be2,
    const float* __restrict__ lw, const float* __restrict__ lb,
    float* __restrict__ dur, const int* __restrict__ target,
    const f32x4* __restrict__ x4, f32x4* __restrict__ out4) {
  __shared__ __attribute__((aligned(16))) char smem[68736];
  // conv:   As [82 rows x 768B) = [0,62976) (x bf16 swizzled; h1 aliases rows 0..65)
  //         stats [80][8][2] f32 = [62976,68096) ; stats2 [80][2] = [68096,68736)
  // gather: ends[512] = [0,2048) ; wsum[8] = [2048,2080) ; idx_s[128] = [2080,2592)

  const int tid = threadIdx.x;
  const int bx  = blockIdx.x;

  if (bx >= NCONV) {
    // ---------------- gather: 128 contiguous out-rows of one batch
    int gi = bx - NCONV;                      // 0..1023
    int* ends  = (int*)smem;
    int* wsum  = (int*)(smem + 2048);
    int* idx_s = (int*)(smem + 2080);
    int b  = gi >> 5;
    int r0 = (gi & 31) * 128;
    int lane = tid & 63, wave = tid >> 6;
    int v = target[b * TIN + tid];
    for (int off = 1; off < 64; off <<= 1) {  // wave-inclusive scan
      int t = __shfl_up(v, off);
      if (lane >= off) v += t;
    }
    if (lane == 63) wsum[wave] = v;
    __syncthreads();
    int base = 0;
    for (int w = 0; w < 8; ++w) base += (w < wave) ? wsum[w] : 0;
    ends[tid] = v + base;                     // inclusive cumsum over 512
    __syncthreads();
    if (tid < 128) {
      int m = r0 + tid;
      int lo = 0, hi = 512;                   // first j with ends[j] > m
      while (lo < hi) {
        int mid = (lo + hi) >> 1;
        if (ends[mid] <= m) lo = mid + 1; else hi = mid;
      }
      idx_s[tid] = (lo < TIN) ? lo : -1;
    }
    __syncthreads();
    const f32x4* xb = x4 + (size_t)b * (TIN * 96);
    f32x4* ob = out4 + ((size_t)b * TOUT + r0) * 96;
    // 24 f32x4/thread in 2 rounds of 12: issue 12 loads (cached; mostly
    // L1/L2 hits on duplicated rows), then 12 NT stores. 12 in flight/wave.
    #pragma unroll
    for (int rd = 0; rd < 2; ++rd) {
      const int jb = rd * 6144;
      f32x4 vv[12];
      #pragma unroll
      for (int k = 0; k < 12; ++k) {
        int j = jb + k * 512 + tid;           // 0..12287
        int row = j / 96;
        int c = j - row * 96;
        int id = idx_s[row];
        vv[k] = (f32x4){0.f, 0.f, 0.f, 0.f};
        if (id >= 0) vv[k] = xb[id * 96 + c];
      }
      #pragma unroll
      for (int k = 0; k < 12; ++k)
        __builtin_nontemporal_store(vv[k], ob + jb + k * 512 + tid);
    }
    return;
  }

  // ---------------- conv block (R5-verbatim)
  char* As = smem;
  float* stats  = (float*)(smem + 62976);     // [80][8][2]
  float* stats2 = (float*)(smem + 68096);     // [80][2] (mean, rstd)

  const int wave = tid >> 6;        // 0..7
  const int lane = tid & 63;
  const int quad = lane >> 4;
  const int l15  = lane & 15;
  const int wn   = wave * 48;
  const int m0   = bx * 64;
  const int b    = m0 >> 9;         // 64-row tiles never cross batch
  const int t0   = m0 & 511;

  // ---- stage A once: rows 0..67 = x[t0-2 .. t0+65], bf16, swizzled
  for (int p = 0; p < 7; ++p) {
    int ch = p * 512 + tid;
    if (ch < 3264) {                          // 68*48
      int row = ch / 48;
      int ci  = ch - row * 48;
      int t   = t0 - 2 + row;
      u16x8 val;
      if ((unsigned)t >= (unsigned)TIN) {
        val = (u16x8)0;
      } else {
        const f32x4* xr = x4 + ((size_t)(b * TIN + t)) * 96 + ci * 2;
        f32x4 v0 = xr[0], v1 = xr[1];
        val[0] = f2bf(v0[0]); val[1] = f2bf(v0[1]); val[2] = f2bf(v0[2]); val[3] = f2bf(v0[3]);
        val[4] = f2bf(v1[0]); val[5] = f2bf(v1[1]); val[6] = f2bf(v1[2]); val[7] = f2bf(v1[3]);
      }
      unsigned int byte = ((unsigned int)(row * 768 + ci * 16)) ^ (((unsigned)row & 7u) << 4);
      *(u16x8*)(As + byte) = val;
    }
  }
  __syncthreads();

  // ================ conv1: 80-row tile (rows 0..65 used), acc 5x3, no barriers
  f32x4 acc[5][3];
  for (int i = 0; i < 5; ++i)
    for (int j = 0; j < 3; ++j)
      acc[i][j] = (f32x4){0.f, 0.f, 0.f, 0.f};

  {
    const unsigned short* Bb = Wt1 + (size_t)(wn + l15) * D_ + quad * 8;
    bf16x8 bvn[3];
    for (int ni = 0; ni < 3; ++ni)
      bvn[ni] = *(const bf16x8*)(Bb + ni * (16 * D_));
    #pragma unroll 1
    for (int kc = 0; kc < 36; ++kc) {
      bf16x8 bv[3];
      bv[0] = bvn[0]; bv[1] = bvn[1]; bv[2] = bvn[2];
      if (kc < 35) {                          // prefetch next k-step's B frags
        int kn = kc + 1;
        int kw2 = kn / 12, d02 = (kn - kw2 * 12) * 32;
        const unsigned short* Bk = Bb + (size_t)kw2 * (F_ * D_) + d02;
        for (int ni = 0; ni < 3; ++ni)
          bvn[ni] = *(const bf16x8*)(Bk + ni * (16 * D_));
      }
      int kw = kc / 12, d0 = (kc - kw * 12) * 32;
      int rb = l15 + kw;
      unsigned int sw = (((unsigned)rb) & 7u) << 4;
      unsigned int base = (unsigned int)(rb * 768 + d0 * 2 + quad * 16);
      bf16x8 av[5];
      for (int mi = 0; mi < 5; ++mi)
        av[mi] = *(const bf16x8*)(As + ((base + mi * 12288) ^ sw));
      for (int mi = 0; mi < 5; ++mi)
        for (int ni = 0; ni < 3; ++ni)
          acc[mi][ni] = __builtin_amdgcn_mfma_f32_16x16x32_bf16(av[mi], bv[ni], acc[mi][ni], 0, 0, 0);
    }
  }

  // ================ epilogue 1: LN(+bias)+relu -> h1 bf16 into As rows 0..65
  {
    float g1v[3], be1v[3], bb1[3];
    for (int ni = 0; ni < 3; ++ni) {
      int c = wn + ni * 16 + l15;
      g1v[ni] = g1[c]; be1v[ni] = be1[c]; bb1[ni] = b1[c];
    }
    for (int mi = 0; mi < 5; ++mi)
      for (int r = 0; r < 4; ++r) {
        float s = 0.f, ssq = 0.f;
        for (int ni = 0; ni < 3; ++ni) {
          float y = acc[mi][ni][r] + bb1[ni];
          s += y; ssq += y * y;
        }
        for (int off = 1; off < 16; off <<= 1) {   // reduce over quad's 16 lanes
          s   += __shfl_xor(s, off);
          ssq += __shfl_xor(ssq, off);
        }
        if (l15 == 0) {
          int row = mi * 16 + quad * 4 + r;
          stats[(row * 8 + wave) * 2 + 0] = s;
          stats[(row * 8 + wave) * 2 + 1] = ssq;
        }
      }
    __syncthreads();
    if (tid < 80) {
      float s = 0.f, ssq = 0.f;
      for (int w = 0; w < 8; ++w) {
        s   += stats[(tid * 8 + w) * 2 + 0];
        ssq += stats[(tid * 8 + w) * 2 + 1];
      }
      float mean = s * (1.f / 384.f);
      float var  = ssq * (1.f / 384.f) - mean * mean;
      stats2[tid * 2 + 0] = mean;
      stats2[tid * 2 + 1] = rsqrtf(var + 1e-5f);
    }
    __syncthreads();
    for (int mi = 0; mi < 5; ++mi)
      for (int r = 0; r < 4; ++r) {
        int row = mi * 16 + quad * 4 + r;
        if (row < 66) {
          float mean = stats2[row * 2 + 0];
          float rstd = stats2[row * 2 + 1];
          int th = t0 - 1 + row;                         // global h1 time
          bool valid = (unsigned)th < (unsigned)TIN;     // t=-1/512 -> zero pad
          unsigned int hb = (((unsigned)row) & 7u) << 4;
          for (int ni = 0; ni < 3; ++ni) {
            float y = (acc[mi][ni][r] + bb1[ni] - mean) * rstd * g1v[ni] + be1v[ni];
            y = y > 0.f ? y : 0.f;
            if (!valid) y = 0.f;
            unsigned int byte = ((unsigned int)(row * 768 + (wn + ni * 16 + l15) * 2)) ^ hb;
            *(unsigned short*)(As + byte) = f2bf(y);
          }
        }
      }
    __syncthreads();                                     // h1 visible
  }

  // ================ conv2: 64-row tile from h1 (LDS), acc 4x3, no barriers
  f32x4 acc2[4][3];
  for (int i = 0; i < 4; ++i)
    for (int j = 0; j < 3; ++j)
      acc2[i][j] = (f32x4){0.f, 0.f, 0.f, 0.f};

  {
    const unsigned short* Bb = Wt2 + (size_t)(wn + l15) * D_ + quad * 8;
    bf16x8 bvn[3];
    for (int ni = 0; ni < 3; ++ni)
      bvn[ni] = *(const bf16x8*)(Bb + ni * (16 * D_));
    #pragma unroll 1
    for (int kc = 0; kc < 36; ++kc) {
      bf16x8 bv[3];
      bv[0] = bvn[0]; bv[1] = bvn[1]; bv[2] = bvn[2];
      if (kc < 35) {
        int kn = kc + 1;
        int kw2 = kn / 12, d02 = (kn - kw2 * 12) * 32;
        const unsigned short* Bk = Bb + (size_t)kw2 * (F_ * D_) + d02;
        for (int ni = 0; ni < 3; ++ni)
          bvn[ni] = *(const bf16x8*)(Bk + ni * (16 * D_));
      }
      int kw = kc / 12, d0 = (kc - kw * 12) * 32;
      int rb = l15 + kw;                       // h1 row = m + kw
      unsigned int sw = (((unsigned)rb) & 7u) << 4;
      unsigned int base = (unsigned int)(rb * 768 + d0 * 2 + quad * 16);
      bf16x8 av[4];
      for (int mi = 0; mi < 4; ++mi)
        av[mi] = *(const bf16x8*)(As + ((base + mi * 12288) ^ sw));
      for (int mi = 0; mi < 4; ++mi)
        for (int ni = 0; ni < 3; ++ni)
          acc2[mi][ni] = __builtin_amdgcn_mfma_f32_16x16x32_bf16(av[mi], bv[ni], acc2[mi][ni], 0, 0, 0);
    }
  }

  // ================ epilogue 2: LN(+bias)+relu+dot(lin_w)+lb -> dur
  {
    float g2v[3], be2v[3], lwv[3], bb2[3];
    for (int ni = 0; ni < 3; ++ni) {
      int c = wn + ni * 16 + l15;
      g2v[ni] = g2[c]; be2v[ni] = be2[c]; lwv[ni] = lw[c]; bb2[ni] = b2[c];
    }
    for (int mi = 0; mi < 4; ++mi)
      for (int r = 0; r < 4; ++r) {
        float s = 0.f, ssq = 0.f;
        for (int ni = 0; ni < 3; ++ni) {
          float y = acc2[mi][ni][r] + bb2[ni];
          s += y; ssq += y * y;
        }
        for (int off = 1; off < 16; off <<= 1) {
          s   += __shfl_xor(s, off);
          ssq += __shfl_xor(ssq, off);
        }
        if (l15 == 0) {
          int row = mi * 16 + quad * 4 + r;
          stats[(row * 8 + wave) * 2 + 0] = s;
          stats[(row * 8 + wave) * 2 + 1] = ssq;
        }
      }
    __syncthreads();
    if (tid < 64) {
      float s = 0.f, ssq = 0.f;
      for (int w = 0; w < 8; ++w) {
        s   += stats[(tid * 8 + w) * 2 + 0];
        ssq += stats[(tid * 8 + w) * 2 + 1];
      }
      float mean = s * (1.f / 384.f);
      float var  = ssq * (1.f / 384.f) - mean * mean;
      stats2[tid * 2 + 0] = mean;
      stats2[tid * 2 + 1] = rsqrtf(var + 1e-5f);
    }
    __syncthreads();
    for (int mi = 0; mi < 4; ++mi)
      for (int r = 0; r < 4; ++r) {
        int row = mi * 16 + quad * 4 + r;
        float mean = stats2[row * 2 + 0];
        float rstd = stats2[row * 2 + 1];
        float a = 0.f;
        for (int ni = 0; ni < 3; ++ni) {
          float y = (acc2[mi][ni][r] + bb2[ni] - mean) * rstd * g2v[ni] + be2v[ni];
          y = y > 0.f ? y : 0.f;
          a += y * lwv[ni];
        }
        for (int off = 1; off < 16; off <<= 1) a += __shfl_xor(a, off);
        if (l15 == 0) stats[(row * 8 + wave) * 2 + 0] = a;
      }
    __syncthreads();
    if (tid < 64) {
      float a = 0.f;
      for (int w = 0; w < 8; ++w) a += stats[(tid * 8 + w) * 2 + 0];
      dur[m0 + tid] = a + lb[0];
    }
  }
}

// ---------------------------------------------------------------- launch
extern "C" void kernel_launch(void* const* d_in, const int* in_sizes, int n_in,
                              void* d_out, int out_size, void* d_ws, size_t ws_size,
                              hipStream_t stream) {
  const float* x      = (const float*)d_in[0];
  const int*   target = (const int*)d_in[1];
  const float* w1  = (const float*)d_in[3];
  const float* b1  = (const float*)d_in[4];
  const float* g1  = (const float*)d_in[5];
  const float* be1 = (const float*)d_in[6];
  const float* w2  = (const float*)d_in[7];
  const float* b2  = (const float*)d_in[8];
  const float* g2  = (const float*)d_in[9];
  const float* be2 = (const float*)d_in[10];
  const float* lw  = (const float*)d_in[11];
  const float* lb  = (const float*)d_in[12];

  float* out = (float*)d_out;
  float* dur = out + (size_t)B_ * TOUT * D_;   // outputs concatenated flat

  char* ws = (char*)d_ws;
  unsigned short* Wt1 = (unsigned short*)(ws);            // 884,736 B
  unsigned short* Wt2 = (unsigned short*)(ws + 884736);   // 884,736 B

  prep_w<<<dim3(1152), dim3(256), 0, stream>>>(w1, w2, Wt1, Wt2);
  fused<<<dim3(NCONV + NGATH), dim3(512), 0, stream>>>(
      Wt1, Wt2, b1, g1, be1, b2, g2, be2, lw, lb,
      dur, target, (const f32x4*)x, (f32x4*)out);
}

// Round 9
// 279.311 us; speedup vs baseline: 1.3137x; 1.0213x over previous
//
#include <hip/hip_runtime.h>
#include <cstdint>
#include <cstddef>

#define B_   32
#define TIN  512
#define D_   384
#define F_   384
#define TOUT 4096

typedef __bf16 bf16x8 __attribute__((ext_vector_type(8)));
typedef float  f32x4  __attribute__((ext_vector_type(4)));
typedef unsigned short u16x8 __attribute__((ext_vector_type(8)));

__device__ __forceinline__ unsigned short f2bf(float f) {
  unsigned int u = __float_as_uint(f);
  u += 0x7fff + ((u >> 16) & 1);   // round-to-nearest-even
  return (unsigned short)(u >> 16);
}

// ---------------------------------------------------------------- prep (weights)
// 1152 blocks x 256: thread e reads w[e*3..+2] (f32, [F][D][K]), writes
// Wt[k][f][d] bf16. Runs before fused (stream order) so Wt is ready.
__global__ __launch_bounds__(256) void prep_w(
    const float* __restrict__ w1, const float* __restrict__ w2,
    unsigned short* __restrict__ Wt1, unsigned short* __restrict__ Wt2) {
  int g = blockIdx.x * 256 + threadIdx.x;     // < 294912
  const int FD = F_ * D_;                     // 147456
  int which = g >= FD;
  const float* w = which ? w2 : w1;
  unsigned short* o = which ? Wt2 : Wt1;
  int e = g - which * FD;                     // f*D_+d
  o[e]          = f2bf(w[e * 3 + 0]);
  o[FD + e]     = f2bf(w[e * 3 + 1]);
  o[2 * FD + e] = f2bf(w[e * 3 + 2]);
}

// ---------------------------------------------------------------- fused kernel
// R5/R8 structure (283.5/285.3µs): grid 1280 x 512thr, 68,736B LDS -> 2 blk/CU.
// Ledger: fused@2blk 283.5/285.3 < split 331-333 ~ fused@1blk 335.6 < 4blk-spill
// 366.9. R8 null: gather ILP 4->12 changed nothing -> not in-flight-limited.
// THIS ROUND'S single variable: nontemporal -> PLAIN stores in gather.
// Evidence for NT-ceiling theory: NT-store kernels show 1.1-3 TB/s write BW
// invariant to occupancy (R2 1blk 1.67, R6 32waves 1.13, R7 32waves ~2.7,
// R8 depth-12 null) while fillBufferAligned (plain stores) hits 6.6 TB/s on
// the same buffer. Cached stores land in L2 full-rate and drain async; the
// nt path appears throttled per-CU. x/Wt eviction risk is L3-absorbed.
#define NCONV 256
#define NGATH 1024

__global__ __launch_bounds__(512, 4) void fused(
    const unsigned short* __restrict__ Wt1, const unsigned short* __restrict__ Wt2,
    const float* __restrict__ b1, const float* __restrict__ g1, const float* __restrict__ be1,
    const float* __restrict__ b2, const float* __restrict__ g2, const float* __restrict__ be2,
    const float* __restrict__ lw, const float* __restrict__ lb,
    float* __restrict__ dur, const int* __restrict__ target,
    const f32x4* __restrict__ x4, f32x4* __restrict__ out4) {
  __shared__ __attribute__((aligned(16))) char smem[68736];
  // conv:   As [82 rows x 768B) = [0,62976) (x bf16 swizzled; h1 aliases rows 0..65)
  //         stats [80][8][2] f32 = [62976,68096) ; stats2 [80][2] = [68096,68736)
  // gather: ends[512] = [0,2048) ; wsum[8] = [2048,2080) ; idx_s[128] = [2080,2592)

  const int tid = threadIdx.x;
  const int bx  = blockIdx.x;

  if (bx >= NCONV) {
    // ---------------- gather: 128 contiguous out-rows of one batch
    int gi = bx - NCONV;                      // 0..1023
    int* ends  = (int*)smem;
    int* wsum  = (int*)(smem + 2048);
    int* idx_s = (int*)(smem + 2080);
    int b  = gi >> 5;
    int r0 = (gi & 31) * 128;
    int lane = tid & 63, wave = tid >> 6;
    int v = target[b * TIN + tid];
    for (int off = 1; off < 64; off <<= 1) {  // wave-inclusive scan
      int t = __shfl_up(v, off);
      if (lane >= off) v += t;
    }
    if (lane == 63) wsum[wave] = v;
    __syncthreads();
    int base = 0;
    for (int w = 0; w < 8; ++w) base += (w < wave) ? wsum[w] : 0;
    ends[tid] = v + base;                     // inclusive cumsum over 512
    __syncthreads();
    if (tid < 128) {
      int m = r0 + tid;
      int lo = 0, hi = 512;                   // first j with ends[j] > m
      while (lo < hi) {
        int mid = (lo + hi) >> 1;
        if (ends[mid] <= m) lo = mid + 1; else hi = mid;
      }
      idx_s[tid] = (lo < TIN) ? lo : -1;
    }
    __syncthreads();
    const f32x4* xb = x4 + (size_t)b * (TIN * 96);
    f32x4* ob = out4 + ((size_t)b * TOUT + r0) * 96;
    // 24 f32x4/thread in 2 rounds of 12: issue 12 loads (L1/L2 hits on
    // duplicated rows), then 12 PLAIN stores (L2 write-back drains at HBM
    // rate; NT path was the throttle).
    #pragma unroll
    for (int rd = 0; rd < 2; ++rd) {
      const int jb = rd * 6144;
      f32x4 vv[12];
      #pragma unroll
      for (int k = 0; k < 12; ++k) {
        int j = jb + k * 512 + tid;           // 0..12287
        int row = j / 96;
        int c = j - row * 96;
        int id = idx_s[row];
        vv[k] = (f32x4){0.f, 0.f, 0.f, 0.f};
        if (id >= 0) vv[k] = xb[id * 96 + c];
      }
      #pragma unroll
      for (int k = 0; k < 12; ++k)
        ob[jb + k * 512 + tid] = vv[k];
    }
    return;
  }

  // ---------------- conv block (R5-verbatim)
  char* As = smem;
  float* stats  = (float*)(smem + 62976);     // [80][8][2]
  float* stats2 = (float*)(smem + 68096);     // [80][2] (mean, rstd)

  const int wave = tid >> 6;        // 0..7
  const int lane = tid & 63;
  const int quad = lane >> 4;
  const int l15  = lane & 15;
  const int wn   = wave * 48;
  const int m0   = bx * 64;
  const int b    = m0 >> 9;         // 64-row tiles never cross batch
  const int t0   = m0 & 511;

  // ---- stage A once: rows 0..67 = x[t0-2 .. t0+65], bf16, swizzled
  for (int p = 0; p < 7; ++p) {
    int ch = p * 512 + tid;
    if (ch < 3264) {                          // 68*48
      int row = ch / 48;
      int ci  = ch - row * 48;
      int t   = t0 - 2 + row;
      u16x8 val;
      if ((unsigned)t >= (unsigned)TIN) {
        val = (u16x8)0;
      } else {
        const f32x4* xr = x4 + ((size_t)(b * TIN + t)) * 96 + ci * 2;
        f32x4 v0 = xr[0], v1 = xr[1];
        val[0] = f2bf(v0[0]); val[1] = f2bf(v0[1]); val[2] = f2bf(v0[2]); val[3] = f2bf(v0[3]);
        val[4] = f2bf(v1[0]); val[5] = f2bf(v1[1]); val[6] = f2bf(v1[2]); val[7] = f2bf(v1[3]);
      }
      unsigned int byte = ((unsigned int)(row * 768 + ci * 16)) ^ (((unsigned)row & 7u) << 4);
      *(u16x8*)(As + byte) = val;
    }
  }
  __syncthreads();

  // ================ conv1: 80-row tile (rows 0..65 used), acc 5x3, no barriers
  f32x4 acc[5][3];
  for (int i = 0; i < 5; ++i)
    for (int j = 0; j < 3; ++j)
      acc[i][j] = (f32x4){0.f, 0.f, 0.f, 0.f};

  {
    const unsigned short* Bb = Wt1 + (size_t)(wn + l15) * D_ + quad * 8;
    bf16x8 bvn[3];
    for (int ni = 0; ni < 3; ++ni)
      bvn[ni] = *(const bf16x8*)(Bb + ni * (16 * D_));
    #pragma unroll 1
    for (int kc = 0; kc < 36; ++kc) {
      bf16x8 bv[3];
      bv[0] = bvn[0]; bv[1] = bvn[1]; bv[2] = bvn[2];
      if (kc < 35) {                          // prefetch next k-step's B frags
        int kn = kc + 1;
        int kw2 = kn / 12, d02 = (kn - kw2 * 12) * 32;
        const unsigned short* Bk = Bb + (size_t)kw2 * (F_ * D_) + d02;
        for (int ni = 0; ni < 3; ++ni)
          bvn[ni] = *(const bf16x8*)(Bk + ni * (16 * D_));
      }
      int kw = kc / 12, d0 = (kc - kw * 12) * 32;
      int rb = l15 + kw;
      unsigned int sw = (((unsigned)rb) & 7u) << 4;
      unsigned int base = (unsigned int)(rb * 768 + d0 * 2 + quad * 16);
      bf16x8 av[5];
      for (int mi = 0; mi < 5; ++mi)
        av[mi] = *(const bf16x8*)(As + ((base + mi * 12288) ^ sw));
      for (int mi = 0; mi < 5; ++mi)
        for (int ni = 0; ni < 3; ++ni)
          acc[mi][ni] = __builtin_amdgcn_mfma_f32_16x16x32_bf16(av[mi], bv[ni], acc[mi][ni], 0, 0, 0);
    }
  }

  // ================ epilogue 1: LN(+bias)+relu -> h1 bf16 into As rows 0..65
  {
    float g1v[3], be1v[3], bb1[3];
    for (int ni = 0; ni < 3; ++ni) {
      int c = wn + ni * 16 + l15;
      g1v[ni] = g1[c]; be1v[ni] = be1[c]; bb1[ni] = b1[c];
    }
    for (int mi = 0; mi < 5; ++mi)
      for (int r = 0; r < 4; ++r) {
        float s = 0.f, ssq = 0.f;
        for (int ni = 0; ni < 3; ++ni) {
          float y = acc[mi][ni][r] + bb1[ni];
          s += y; ssq += y * y;
        }
        for (int off = 1; off < 16; off <<= 1) {   // reduce over quad's 16 lanes
          s   += __shfl_xor(s, off);
          ssq += __shfl_xor(ssq, off);
        }
        if (l15 == 0) {
          int row = mi * 16 + quad * 4 + r;
          stats[(row * 8 + wave) * 2 + 0] = s;
          stats[(row * 8 + wave) * 2 + 1] = ssq;
        }
      }
    __syncthreads();
    if (tid < 80) {
      float s = 0.f, ssq = 0.f;
      for (int w = 0; w < 8; ++w) {
        s   += stats[(tid * 8 + w) * 2 + 0];
        ssq += stats[(tid * 8 + w) * 2 + 1];
      }
      float mean = s * (1.f / 384.f);
      float var  = ssq * (1.f / 384.f) - mean * mean;
      stats2[tid * 2 + 0] = mean;
      stats2[tid * 2 + 1] = rsqrtf(var + 1e-5f);
    }
    __syncthreads();
    for (int mi = 0; mi < 5; ++mi)
      for (int r = 0; r < 4; ++r) {
        int row = mi * 16 + quad * 4 + r;
        if (row < 66) {
          float mean = stats2[row * 2 + 0];
          float rstd = stats2[row * 2 + 1];
          int th = t0 - 1 + row;                         // global h1 time
          bool valid = (unsigned)th < (unsigned)TIN;     // t=-1/512 -> zero pad
          unsigned int hb = (((unsigned)row) & 7u) << 4;
          for (int ni = 0; ni < 3; ++ni) {
            float y = (acc[mi][ni][r] + bb1[ni] - mean) * rstd * g1v[ni] + be1v[ni];
            y = y > 0.f ? y : 0.f;
            if (!valid) y = 0.f;
            unsigned int byte = ((unsigned int)(row * 768 + (wn + ni * 16 + l15) * 2)) ^ hb;
            *(unsigned short*)(As + byte) = f2bf(y);
          }
        }
      }
    __syncthreads();                                     // h1 visible
  }

  // ================ conv2: 64-row tile from h1 (LDS), acc 4x3, no barriers
  f32x4 acc2[4][3];
  for (int i = 0; i < 4; ++i)
    for (int j = 0; j < 3; ++j)
      acc2[i][j] = (f32x4){0.f, 0.f, 0.f, 0.f};

  {
    const unsigned short* Bb = Wt2 + (size_t)(wn + l15) * D_ + quad * 8;
    bf16x8 bvn[3];
    for (int ni = 0; ni < 3; ++ni)
      bvn[ni] = *(const bf16x8*)(Bb + ni * (16 * D_));
    #pragma unroll 1
    for (int kc = 0; kc < 36; ++kc) {
      bf16x8 bv[3];
      bv[0] = bvn[0]; bv[1] = bvn[1]; bv[2] = bvn[2];
      if (kc < 35) {
        int kn = kc + 1;
        int kw2 = kn / 12, d02 = (kn - kw2 * 12) * 32;
        const unsigned short* Bk = Bb + (size_t)kw2 * (F_ * D_) + d02;
        for (int ni = 0; ni < 3; ++ni)
          bvn[ni] = *(const bf16x8*)(Bk + ni * (16 * D_));
      }
      int kw = kc / 12, d0 = (kc - kw * 12) * 32;
      int rb = l15 + kw;                       // h1 row = m + kw
      unsigned int sw = (((unsigned)rb) & 7u) << 4;
      unsigned int base = (unsigned int)(rb * 768 + d0 * 2 + quad * 16);
      bf16x8 av[4];
      for (int mi = 0; mi < 4; ++mi)
        av[mi] = *(const bf16x8*)(As + ((base + mi * 12288) ^ sw));
      for (int mi = 0; mi < 4; ++mi)
        for (int ni = 0; ni < 3; ++ni)
          acc2[mi][ni] = __builtin_amdgcn_mfma_f32_16x16x32_bf16(av[mi], bv[ni], acc2[mi][ni], 0, 0, 0);
    }
  }

  // ================ epilogue 2: LN(+bias)+relu+dot(lin_w)+lb -> dur
  {
    float g2v[3], be2v[3], lwv[3], bb2[3];
    for (int ni = 0; ni < 3; ++ni) {
      int c = wn + ni * 16 + l15;
      g2v[ni] = g2[c]; be2v[ni] = be2[c]; lwv[ni] = lw[c]; bb2[ni] = b2[c];
    }
    for (int mi = 0; mi < 4; ++mi)
      for (int r = 0; r < 4; ++r) {
        float s = 0.f, ssq = 0.f;
        for (int ni = 0; ni < 3; ++ni) {
          float y = acc2[mi][ni][r] + bb2[ni];
          s += y; ssq += y * y;
        }
        for (int off = 1; off < 16; off <<= 1) {
          s   += __shfl_xor(s, off);
          ssq += __shfl_xor(ssq, off);
        }
        if (l15 == 0) {
          int row = mi * 16 + quad * 4 + r;
          stats[(row * 8 + wave) * 2 + 0] = s;
          stats[(row * 8 + wave) * 2 + 1] = ssq;
        }
      }
    __syncthreads();
    if (tid < 64) {
      float s = 0.f, ssq = 0.f;
      for (int w = 0; w < 8; ++w) {
        s   += stats[(tid * 8 + w) * 2 + 0];
        ssq += stats[(tid * 8 + w) * 2 + 1];
      }
      float mean = s * (1.f / 384.f);
      float var  = ssq * (1.f / 384.f) - mean * mean;
      stats2[tid * 2 + 0] = mean;
      stats2[tid * 2 + 1] = rsqrtf(var + 1e-5f);
    }
    __syncthreads();
    for (int mi = 0; mi < 4; ++mi)
      for (int r = 0; r < 4; ++r) {
        int row = mi * 16 + quad * 4 + r;
        float mean = stats2[row * 2 + 0];
        float rstd = stats2[row * 2 + 1];
        float a = 0.f;
        for (int ni = 0; ni < 3; ++ni) {
          float y = (acc2[mi][ni][r] + bb2[ni] - mean) * rstd * g2v[ni] + be2v[ni];
          y = y > 0.f ? y : 0.f;
          a += y * lwv[ni];
        }
        for (int off = 1; off < 16; off <<= 1) a += __shfl_xor(a, off);
        if (l15 == 0) stats[(row * 8 + wave) * 2 + 0] = a;
      }
    __syncthreads();
    if (tid < 64) {
      float a = 0.f;
      for (int w = 0; w < 8; ++w) a += stats[(tid * 8 + w) * 2 + 0];
      dur[m0 + tid] = a + lb[0];
    }
  }
}

// ---------------------------------------------------------------- launch
extern "C" void kernel_launch(void* const* d_in, const int* in_sizes, int n_in,
                              void* d_out, int out_size, void* d_ws, size_t ws_size,
                              hipStream_t stream) {
  const float* x      = (const float*)d_in[0];
  const int*   target = (const int*)d_in[1];
  const float* w1  = (const float*)d_in[3];
  const float* b1  = (const float*)d_in[4];
  const float* g1  = (const float*)d_in[5];
  const float* be1 = (const float*)d_in[6];
  const float* w2  = (const float*)d_in[7];
  const float* b2  = (const float*)d_in[8];
  const float* g2  = (const float*)d_in[9];
  const float* be2 = (const float*)d_in[10];
  const float* lw  = (const float*)d_in[11];
  const float* lb  = (const float*)d_in[12];

  float* out = (float*)d_out;
  float* dur = out + (size_t)B_ * TOUT * D_;   // outputs concatenated flat

  char* ws = (char*)d_ws;
  unsigned short* Wt1 = (unsigned short*)(ws);            // 884,736 B
  unsigned short* Wt2 = (unsigned short*)(ws + 884736);   // 884,736 B

  prep_w<<<dim3(1152), dim3(256), 0, stream>>>(w1, w2, Wt1, Wt2);
  fused<<<dim3(NCONV + NGATH), dim3(512), 0, stream>>>(
      Wt1, Wt2, b1, g1, be1, b2, g2, be2, lw, lb,
      dur, target, (const f32x4*)x, (f32x4*)out);
}